// Round 3
// baseline (286.517 us; speedup 1.0000x reference)
//
#include <hip/hip_runtime.h>
#include <hip/hip_bf16.h>

// InfoNCE: a[4096,512], p[4096,512], n[16384,512] f32 -> 4 f32 scalars.
// R7: double-buffered K-pipeline with COUNTED vmcnt (T3+T4) + setprio (T5).
//     R6 post-mortem: XCD swizzle regressed (default round-robin already
//     partitions n-tiles per XCD since GX%8==0) -> dropped. Real bottleneck:
//     63% both-pipes-idle from the per-K-tile vmcnt(0)+barrier drain (8 fully
//     exposed latency windows per block at K=512). Fix: BK=64 double buffer
//     (2x16KB, same 32KB total -> occupancy unchanged), issue next tile's 4
//     global_load_lds BEFORE computing current, s_waitcnt vmcnt(4) keeps the
//     prefetch in flight across the barrier (never vmcnt(0) in the loop).
//     BK=64 granule scheme: quad q reads true granule q of each row (1 b128
//     per frag-row per K-tile, halves = the 2 k-step MFMA operands; same
//     mapping for A and B -> dot exact). XOR-swizzle by (row>>1)&3: uniform
//     2-way banks (free), linear LDS dest + inverse-swizzled source.
// ws layout: a8(2MB) p8(2MB) n8(8MB) | S[4096] csA[512*16] csP[512*16] csN[512*16] lsum[1]

#define D_DIM 512
#define B_ROWS 4096
#define P_ROWS 4096
#define N_ROWS 16384
#define INV_T 14.285714285714286f
#define EPS_L 1e-8f
#define CS_STRIDE 16  // colsum accumulators spread 64B apart -> atomics hit distinct lines

typedef unsigned char fp8_t;
typedef __attribute__((ext_vector_type(4))) float floatx4;   // MFMA C/D frag
typedef __attribute__((ext_vector_type(2))) long longx2;     // 16B LDS read = 2 MFMA operands
typedef unsigned int uint32;

// ---- fused: L2-normalize rows -> fp8 e4m3, and accumulate fp32 column sums ----
// grid = 1024 blocks x 256 thr. Segments: b<256 -> A, b<512 -> P, else -> N.
__global__ __launch_bounds__(256) void norm_colsum(
        const float* __restrict__ a, const float* __restrict__ p, const float* __restrict__ n,
        fp8_t* __restrict__ a8, fp8_t* __restrict__ p8, fp8_t* __restrict__ n8,
        float* __restrict__ csA, float* __restrict__ csP, float* __restrict__ csN) {
    const float* in; fp8_t* outp; float* cs; int rows, nb, bseg;
    int b = blockIdx.x;
    if (b < 256)      { in = a; outp = a8; cs = csA; rows = B_ROWS; nb = 256; bseg = b; }
    else if (b < 512) { in = p; outp = p8; cs = csP; rows = P_ROWS; nb = 256; bseg = b - 256; }
    else              { in = n; outp = n8; cs = csN; rows = N_ROWS; nb = 512; bseg = b - 512; }

    const int wave = threadIdx.x >> 6;
    const int lane = threadIdx.x & 63;

    float cs0[4] = {0.f, 0.f, 0.f, 0.f};
    float cs1[4] = {0.f, 0.f, 0.f, 0.f};

    for (int chunk = bseg; chunk < (rows >> 2); chunk += nb) {
        int r = chunk * 4 + wave;
        const float4* rp = reinterpret_cast<const float4*>(in + (size_t)r * D_DIM);
        float4 v0 = rp[lane];
        float4 v1 = rp[lane + 64];
        float ss = v0.x*v0.x + v0.y*v0.y + v0.z*v0.z + v0.w*v0.w
                 + v1.x*v1.x + v1.y*v1.y + v1.z*v1.z + v1.w*v1.w;
#pragma unroll
        for (int off = 1; off < 64; off <<= 1) ss += __shfl_xor(ss, off);
        float inv = 1.0f / fmaxf(sqrtf(ss), 1e-12f);
        float f0x = v0.x*inv, f0y = v0.y*inv, f0z = v0.z*inv, f0w = v0.w*inv;
        float f1x = v1.x*inv, f1y = v1.y*inv, f1z = v1.z*inv, f1w = v1.w*inv;
        cs0[0] += f0x; cs0[1] += f0y; cs0[2] += f0z; cs0[3] += f0w;
        cs1[0] += f1x; cs1[1] += f1y; cs1[2] += f1z; cs1[3] += f1w;
        // pack 4 floats -> 4 fp8 e4m3 bytes (RNE hw cvt)
        int pk0 = __builtin_amdgcn_cvt_pk_fp8_f32(f0x, f0y, 0, 0);
        pk0     = __builtin_amdgcn_cvt_pk_fp8_f32(f0z, f0w, pk0, 1);
        int pk1 = __builtin_amdgcn_cvt_pk_fp8_f32(f1x, f1y, 0, 0);
        pk1     = __builtin_amdgcn_cvt_pk_fp8_f32(f1z, f1w, pk1, 1);
        uint32* op = reinterpret_cast<uint32*>(outp + (size_t)r * D_DIM);
        op[lane]      = (uint32)pk0;   // bytes 4*lane .. 4*lane+3
        op[lane + 64] = (uint32)pk1;   // bytes 256+4*lane ..
    }

    // block-level colsum reduce: LDS atomics (4-way max contention), then one
    // global atomic per column per block, spread across 64B lines.
    __shared__ float csh[D_DIM];
    if (threadIdx.x < 256) { csh[threadIdx.x] = 0.f; csh[threadIdx.x + 256] = 0.f; }
    __syncthreads();
#pragma unroll
    for (int j = 0; j < 4; ++j) {
        atomicAdd(&csh[lane * 4 + j], cs0[j]);
        atomicAdd(&csh[256 + lane * 4 + j], cs1[j]);
    }
    __syncthreads();
    if (threadIdx.x < 256) {
        atomicAdd(&cs[(size_t)threadIdx.x * CS_STRIDE], csh[threadIdx.x]);
        atomicAdd(&cs[(size_t)(threadIdx.x + 256) * CS_STRIDE], csh[threadIdx.x + 256]);
    }
}

// ---------------- fp8 MFMA GEMM, dbuf K-pipeline, fused epilogue ----------------
#define BM 128
#define BN 128
#define BKB 64   // K-elements per tile == bytes per row per tile (fp8)
#define NKT 8    // 512 / 64 K-tiles

typedef const __attribute__((address_space(1))) unsigned int* as1_u32p;
typedef __attribute__((address_space(3))) unsigned int* as3_u32p;

__device__ __forceinline__ void load_lds16(const void* g, void* l) {
    // each lane writes 16B at (wave-uniform l) + lane*16
    __builtin_amdgcn_global_load_lds((as1_u32p)g, (as3_u32p)l, 16, 0, 0);
}

// EPI==0: C = A@Bm^T, S[row] += sum_col exp(C*invT)           (neg pass)
// EPI==1: loss_sum += sum(-log(exp(C*invT)/(exp+S[row])+eps)) (pos pass)
template <int EPI>
__global__ __launch_bounds__(256, 4) void gemm_epi(const fp8_t* __restrict__ A,
                                                   const fp8_t* __restrict__ Bm,
                                                   float* __restrict__ S,
                                                   float* __restrict__ loss_sum) {
    __shared__ fp8_t As[2][BM * BKB];  // 2 x 8 KB
    __shared__ fp8_t Bs[2][BN * BKB];  // 2 x 8 KB   (32 KB total, as before)

    const int tid  = threadIdx.x;
    const int lane = tid & 63;
    const int w    = tid >> 6;          // wave 0..3
    const int wm   = w >> 1, wn = w & 1;
    const int m0   = blockIdx.y * BM;
    const int n0   = blockIdx.x * BN;
    const int lr   = lane & 15;         // row-in-16-tile for frags (= output col)
    const int q    = lane >> 4;         // quad 0..3

    // staging addressing: each load_lds16 covers 16 rows x 64B (1KB/wave).
    // lane l -> row sr=l>>2, LDS slot l&3; source granule inverse-swizzled so
    // LDS[r*64 + 16*s] holds true granule s ^ ((r>>1)&3) of row r.
    const int sr = lane >> 2;                        // 0..15
    const int sg = (lane & 3) ^ ((lane >> 3) & 3);   // source granule
    // fragment read: lane reads true granule q of its row -> LDS slot q^((r>>1)&3).
    const int goff = ((q ^ ((lr >> 1) & 3)) << 4);   // same for every rt/ct

    floatx4 acc[4][4];
#pragma unroll
    for (int i = 0; i < 4; ++i)
#pragma unroll
        for (int j = 0; j < 4; ++j) acc[i][j] = (floatx4){0.f, 0.f, 0.f, 0.f};

    // prologue: stage K-tile 0 into buf 0 (4 loads/wave -> vmcnt 4)
#pragma unroll
    for (int i = 0; i < 2; ++i) {
        int rbase = w * 32 + i * 16;
        load_lds16(A  + (size_t)(m0 + rbase + sr) * D_DIM + sg * 16, &As[0][rbase * BKB]);
        load_lds16(Bm + (size_t)(n0 + rbase + sr) * D_DIM + sg * 16, &Bs[0][rbase * BKB]);
    }

#pragma unroll
    for (int kt = 0; kt < NKT; ++kt) {
        const int cur = kt & 1;
        if (kt < NKT - 1) {
            // issue next tile's staging; it stays in flight across the barrier
            const int koff = (kt + 1) * BKB + sg * 16;
#pragma unroll
            for (int i = 0; i < 2; ++i) {
                int rbase = w * 32 + i * 16;
                load_lds16(A  + (size_t)(m0 + rbase + sr) * D_DIM + koff, &As[cur ^ 1][rbase * BKB]);
                load_lds16(Bm + (size_t)(n0 + rbase + sr) * D_DIM + koff, &Bs[cur ^ 1][rbase * BKB]);
            }
            asm volatile("s_waitcnt vmcnt(4)" ::: "memory");  // cur's 4 done, next's 4 in flight
        } else {
            asm volatile("s_waitcnt vmcnt(0)" ::: "memory");  // last tile: drain
        }
        __builtin_amdgcn_sched_barrier(0);
        __builtin_amdgcn_s_barrier();    // all waves' cur staging complete
        __builtin_amdgcn_sched_barrier(0);

        longx2 af[4], bfr[4];
#pragma unroll
        for (int rt = 0; rt < 4; ++rt) {
            int r = wm * 64 + rt * 16 + lr;
            af[rt] = *reinterpret_cast<const longx2*>(&As[cur][r * BKB + goff]);
        }
#pragma unroll
        for (int ct = 0; ct < 4; ++ct) {
            int r = wn * 64 + ct * 16 + lr;
            bfr[ct] = *reinterpret_cast<const longx2*>(&Bs[cur][r * BKB + goff]);
        }
        // quad q holds true k in [16q,16q+8) (.x) and [16q+8,16q+16) (.y):
        // identical permuted k-mapping for A and B -> exact dot product.
        __builtin_amdgcn_s_setprio(1);
#pragma unroll
        for (int rt = 0; rt < 4; ++rt)
#pragma unroll
            for (int ct = 0; ct < 4; ++ct)
                acc[rt][ct] = __builtin_amdgcn_mfma_f32_16x16x32_fp8_fp8(af[rt].x, bfr[ct].x,
                                                                         acc[rt][ct], 0, 0, 0);
#pragma unroll
        for (int rt = 0; rt < 4; ++rt)
#pragma unroll
            for (int ct = 0; ct < 4; ++ct)
                acc[rt][ct] = __builtin_amdgcn_mfma_f32_16x16x32_fp8_fp8(af[rt].y, bfr[ct].y,
                                                                         acc[rt][ct], 0, 0, 0);
        __builtin_amdgcn_s_setprio(0);
        __builtin_amdgcn_sched_barrier(0);
        __builtin_amdgcn_s_barrier();    // reads of buf[cur] done before overwrite
    }

    // C/D layout: col = lane&15, row = (lane>>4)*4 + reg
    if (EPI == 0) {
#pragma unroll
        for (int rt = 0; rt < 4; ++rt) {
#pragma unroll
            for (int reg = 0; reg < 4; ++reg) {
                float v = 0.f;
#pragma unroll
                for (int ct = 0; ct < 4; ++ct) v += __expf(acc[rt][ct][reg] * INV_T);
                v += __shfl_xor(v, 1);
                v += __shfl_xor(v, 2);
                v += __shfl_xor(v, 4);
                v += __shfl_xor(v, 8);
                if (lr == 0) {
                    int row = m0 + wm * 64 + rt * 16 + q * 4 + reg;
                    atomicAdd(&S[row], v);
                }
            }
        }
    } else {
        float lsum = 0.f;
#pragma unroll
        for (int rt = 0; rt < 4; ++rt) {
#pragma unroll
            for (int reg = 0; reg < 4; ++reg) {
                int row = m0 + wm * 64 + rt * 16 + q * 4 + reg;
                float Sv = S[row];
#pragma unroll
                for (int ct = 0; ct < 4; ++ct) {
                    float pe = __expf(acc[rt][ct][reg] * INV_T);
                    lsum -= __logf(pe / (pe + Sv) + EPS_L);
                }
            }
        }
#pragma unroll
        for (int off = 1; off < 64; off <<= 1) lsum += __shfl_xor(lsum, off);
        if (lane == 0) atomicAdd(loss_sum, lsum);
    }
}

// ---- finalize: dot the (strided) column sums, emit the 4 scalars ----
__global__ void finalize_k(const float* __restrict__ csA, const float* __restrict__ csP,
                           const float* __restrict__ csN, const float* __restrict__ lsum,
                           float* __restrict__ out) {
    int tid = threadIdx.x;  // 512
    float av = csA[(size_t)tid * CS_STRIDE];
    float dp = av * csP[(size_t)tid * CS_STRIDE];
    float dn = av * csN[(size_t)tid * CS_STRIDE];
#pragma unroll
    for (int off = 1; off < 64; off <<= 1) {
        dp += __shfl_xor(dp, off);
        dn += __shfl_xor(dn, off);
    }
    __shared__ float red[16];
    int wid = tid >> 6, lane = tid & 63;
    if (lane == 0) { red[wid] = dp; red[8 + wid] = dn; }
    __syncthreads();
    if (tid == 0) {
        float sdp = 0.f, sdn = 0.f;
#pragma unroll
        for (int i = 0; i < 8; ++i) { sdp += red[i]; sdn += red[8 + i]; }
        float mean_pos = sdp * INV_T / ((float)B_ROWS * (float)P_ROWS);
        float mean_neg = sdn * INV_T / ((float)B_ROWS * (float)N_ROWS);
        out[0] = lsum[0] / ((float)B_ROWS * (float)P_ROWS);
        out[1] = mean_pos;
        out[2] = mean_neg;
        out[3] = mean_pos - mean_neg;
    }
}

extern "C" void kernel_launch(void* const* d_in, const int* in_sizes, int n_in,
                              void* d_out, int out_size, void* d_ws, size_t ws_size,
                              hipStream_t stream) {
    const float* anc = (const float*)d_in[0];
    const float* pos = (const float*)d_in[1];
    const float* neg = (const float*)d_in[2];
    float* out = (float*)d_out;

    fp8_t* a8 = (fp8_t*)d_ws;
    fp8_t* p8 = a8 + (size_t)B_ROWS * D_DIM;
    fp8_t* n8 = p8 + (size_t)P_ROWS * D_DIM;
    float* fsec = (float*)(n8 + (size_t)N_ROWS * D_DIM);  // 12MB offset, 64B-aligned
    float* S    = fsec;                        // 4096
    float* csA  = S + B_ROWS;                  // 512*16
    float* csP  = csA + D_DIM * CS_STRIDE;     // 512*16
    float* csN  = csP + D_DIM * CS_STRIDE;     // 512*16
    float* lsum = csN + D_DIM * CS_STRIDE;     // 1

    // ws is re-poisoned 0xAA before every launch -> zero all accumulators
    hipMemsetAsync(fsec, 0, (B_ROWS + 3 * D_DIM * CS_STRIDE + 1) * sizeof(float), stream);

    norm_colsum<<<1024, 256, 0, stream>>>(anc, pos, neg, a8, p8, n8, csA, csP, csN);

    gemm_epi<0><<<dim3(N_ROWS / BN, B_ROWS / BM), 256, 0, stream>>>(a8, n8, S, nullptr);
    gemm_epi<1><<<dim3(P_ROWS / BN, B_ROWS / BM), 256, 0, stream>>>(a8, p8, S, lsum);

    finalize_k<<<1, 512, 0, stream>>>(csA, csP, csN, lsum, out);
}

// Round 4
// 219.544 us; speedup vs baseline: 1.3051x; 1.3051x over previous
//
#include <hip/hip_runtime.h>
#include <hip/hip_bf16.h>

// InfoNCE: a[4096,512], p[4096,512], n[16384,512] f32 -> 4 f32 scalars.
// R8: persistent-A blocks. R7 post-mortem: counted-vmcnt dbuf == R4 (109.5 vs
//     110us, MfmaUtil ~25%) -> the 2-phase skeleton itself is the cost and
//     K=512 gives only 4-8 loop iterations (prologue/drain-dominated; m145's
//     identical structure hits 45% at K=4096). Fix the DEPTH, not the waits:
//     full-K A-panel (64KB fp8) stays resident in LDS for the whole block;
//     each block sweeps TN n-tiles re-using it -> 8*TN-iteration loop (64 for
//     gemm0) of {2 B-stage loads, vmcnt(2), barrier, 8 ds_read, 32 MFMA,
//     barrier}. B dbuf 2x8KB. LDS 80KB -> 2 blocks/CU, 1 wave of each block
//     per SIMD -> cross-block overlap covers barrier stalls. Epilogues are
//     register-only inside the loop (atomics hoisted) so vmcnt counts stay
//     exact. A stride-512 layout keeps the measured-conflict-free 8-lane
//     phase tiling via parity swizzle: true granule KT*4+g of row r stored at
//     r*512 + (KT^(r&1))*64 + (g^((r>>1)&3))*16.
// ws layout: a8(2MB) p8(2MB) n8(8MB) | S[4096] csA[512*16] csP[512*16] csN[512*16] lsum[1]

#define D_DIM 512
#define B_ROWS 4096
#define P_ROWS 4096
#define N_ROWS 16384
#define INV_T 14.285714285714286f
#define EPS_L 1e-8f
#define CS_STRIDE 16  // colsum accumulators spread 64B apart -> atomics hit distinct lines

typedef unsigned char fp8_t;
typedef __attribute__((ext_vector_type(4))) float floatx4;   // MFMA C/D frag
typedef __attribute__((ext_vector_type(2))) long longx2;     // 16B LDS read = 2 MFMA operands
typedef unsigned int uint32;

// ---- fused: L2-normalize rows -> fp8 e4m3, and accumulate fp32 column sums ----
// grid = 1024 blocks x 256 thr. Segments: b<256 -> A, b<512 -> P, else -> N.
__global__ __launch_bounds__(256) void norm_colsum(
        const float* __restrict__ a, const float* __restrict__ p, const float* __restrict__ n,
        fp8_t* __restrict__ a8, fp8_t* __restrict__ p8, fp8_t* __restrict__ n8,
        float* __restrict__ csA, float* __restrict__ csP, float* __restrict__ csN) {
    const float* in; fp8_t* outp; float* cs; int rows, nb, bseg;
    int b = blockIdx.x;
    if (b < 256)      { in = a; outp = a8; cs = csA; rows = B_ROWS; nb = 256; bseg = b; }
    else if (b < 512) { in = p; outp = p8; cs = csP; rows = P_ROWS; nb = 256; bseg = b - 256; }
    else              { in = n; outp = n8; cs = csN; rows = N_ROWS; nb = 512; bseg = b - 512; }

    const int wave = threadIdx.x >> 6;
    const int lane = threadIdx.x & 63;

    float cs0[4] = {0.f, 0.f, 0.f, 0.f};
    float cs1[4] = {0.f, 0.f, 0.f, 0.f};

    for (int chunk = bseg; chunk < (rows >> 2); chunk += nb) {
        int r = chunk * 4 + wave;
        const float4* rp = reinterpret_cast<const float4*>(in + (size_t)r * D_DIM);
        float4 v0 = rp[lane];
        float4 v1 = rp[lane + 64];
        float ss = v0.x*v0.x + v0.y*v0.y + v0.z*v0.z + v0.w*v0.w
                 + v1.x*v1.x + v1.y*v1.y + v1.z*v1.z + v1.w*v1.w;
#pragma unroll
        for (int off = 1; off < 64; off <<= 1) ss += __shfl_xor(ss, off);
        float inv = 1.0f / fmaxf(sqrtf(ss), 1e-12f);
        float f0x = v0.x*inv, f0y = v0.y*inv, f0z = v0.z*inv, f0w = v0.w*inv;
        float f1x = v1.x*inv, f1y = v1.y*inv, f1z = v1.z*inv, f1w = v1.w*inv;
        cs0[0] += f0x; cs0[1] += f0y; cs0[2] += f0z; cs0[3] += f0w;
        cs1[0] += f1x; cs1[1] += f1y; cs1[2] += f1z; cs1[3] += f1w;
        // pack 4 floats -> 4 fp8 e4m3 bytes (RNE hw cvt)
        int pk0 = __builtin_amdgcn_cvt_pk_fp8_f32(f0x, f0y, 0, 0);
        pk0     = __builtin_amdgcn_cvt_pk_fp8_f32(f0z, f0w, pk0, 1);
        int pk1 = __builtin_amdgcn_cvt_pk_fp8_f32(f1x, f1y, 0, 0);
        pk1     = __builtin_amdgcn_cvt_pk_fp8_f32(f1z, f1w, pk1, 1);
        uint32* op = reinterpret_cast<uint32*>(outp + (size_t)r * D_DIM);
        op[lane]      = (uint32)pk0;   // bytes 4*lane .. 4*lane+3
        op[lane + 64] = (uint32)pk1;   // bytes 256+4*lane ..
    }

    // block-level colsum reduce: LDS atomics (4-way max contention), then one
    // global atomic per column per block, spread across 64B lines.
    __shared__ float csh[D_DIM];
    if (threadIdx.x < 256) { csh[threadIdx.x] = 0.f; csh[threadIdx.x + 256] = 0.f; }
    __syncthreads();
#pragma unroll
    for (int j = 0; j < 4; ++j) {
        atomicAdd(&csh[lane * 4 + j], cs0[j]);
        atomicAdd(&csh[256 + lane * 4 + j], cs1[j]);
    }
    __syncthreads();
    if (threadIdx.x < 256) {
        atomicAdd(&cs[(size_t)threadIdx.x * CS_STRIDE], csh[threadIdx.x]);
        atomicAdd(&cs[(size_t)(threadIdx.x + 256) * CS_STRIDE], csh[threadIdx.x + 256]);
    }
}

// ---------------- fp8 MFMA GEMM, persistent-A, B-dbuf deep pipeline ----------------
#define BM 128
#define BN 128
#define BKB 64   // K-elements per B tile == bytes per row per tile (fp8)

typedef const __attribute__((address_space(1))) unsigned int* as1_u32p;
typedef __attribute__((address_space(3))) unsigned int* as3_u32p;

__device__ __forceinline__ void load_lds16(const void* g, void* l) {
    // each lane writes 16B at (wave-uniform l) + lane*16
    __builtin_amdgcn_global_load_lds((as1_u32p)g, (as3_u32p)l, 16, 0, 0);
}

// EPI==0: C = A@Bm^T, S[row] += sum_col exp(C*invT)           (neg pass)
// EPI==1: loss_sum += sum(-log(exp(C*invT)/(exp+S[row])+eps)) (pos pass)
// Block: 1 m-tile x TN consecutive n-tiles, A resident in LDS all-K.
template <int EPI, int TN>
__global__ __launch_bounds__(256, 2) void gemm_epi(const fp8_t* __restrict__ A,
                                                   const fp8_t* __restrict__ Bm,
                                                   float* __restrict__ S,
                                                   float* __restrict__ loss_sum) {
    __shared__ fp8_t Al[BM * D_DIM];    // 64 KB: full-K A panel, parity-swizzled
    __shared__ fp8_t Bl[2][BN * BKB];   // 2 x 8 KB B double-buffer

    const int tid  = threadIdx.x;
    const int lane = tid & 63;
    const int w    = tid >> 6;          // wave 0..3
    const int wm   = w >> 1, wn = w & 1;
    const int m0   = blockIdx.y * BM;
    const int nt0  = blockIdx.x * TN;   // first n-tile index
    const int lr   = lane & 15;         // row-in-16-tile for frags (= output col)
    const int q    = lane >> 4;         // quad 0..3

    // ---- A prologue: full-K panel, 16 loads/wave (2 rows x 512B each) ----
    // storage: true granule KT*4+g of row r at r*512+(KT^(r&1))*64+(g^((r>>1)&3))*16
    // lane l of load i writes LDS r0*512 + l*16 (r0=w*32+i*2, r=r0+(l>>5));
    // stored KT'=(l&31)>>2, slot=l&3 -> fetch true G = ((KT'^(l>>5))<<2)|((l&3)^(i&3)).
    {
        const int rh = lane >> 5;        // row within the 2-row pair
        const int c5 = lane & 31;        // stored 16B column 0..31
#pragma unroll
        for (int i = 0; i < 16; ++i) {
            int r0 = w * 32 + i * 2;     // even, wave-uniform
            int G  = (((c5 >> 2) ^ rh) << 2) | ((lane & 3) ^ (i & 3));
            load_lds16(A + (size_t)(m0 + r0 + rh) * D_DIM + G * 16, &Al[r0 * D_DIM]);
        }
    }

    // ---- B staging constants (identical scheme to R7, stride 64) ----
    const int sr = lane >> 2;                        // row 0..15 within 16-row load
    const int sg = (lane & 3) ^ ((lane >> 3) & 3);   // inverse-swizzled source granule
    const fp8_t* bbase = Bm + (size_t)(nt0 * BN + w * 32 + sr) * D_DIM + sg * 16;

    // stage B tile 0
#pragma unroll
    for (int i = 0; i < 2; ++i)
        load_lds16(bbase + (size_t)(i * 16) * D_DIM, &Bl[0][(w * 32 + i * 16) * BKB]);
    __syncthreads();   // vmcnt(0)+barrier: A panel + B tile0 resident

    const int goff = ((q ^ ((lr >> 1) & 3)) << 4);

    float vac[4][4];   // EPI0: per-lane exp-sum partials, accumulated across n-tiles
    float Sv[4][4];    // EPI1: cached denominators (rows fixed per block)
    float lsum = 0.f;
    if (EPI == 0) {
#pragma unroll
        for (int rt = 0; rt < 4; ++rt)
#pragma unroll
            for (int reg = 0; reg < 4; ++reg) vac[rt][reg] = 0.f;
    } else {
#pragma unroll
        for (int rt = 0; rt < 4; ++rt)
#pragma unroll
            for (int reg = 0; reg < 4; ++reg)
                Sv[rt][reg] = S[m0 + wm * 64 + rt * 16 + q * 4 + reg];
    }

    for (int j = 0; j < TN; ++j) {
        floatx4 acc[4][4];
#pragma unroll
        for (int i = 0; i < 4; ++i)
#pragma unroll
            for (int jj = 0; jj < 4; ++jj) acc[i][jj] = (floatx4){0.f, 0.f, 0.f, 0.f};

#pragma unroll
        for (int kt = 0; kt < 8; ++kt) {
            const int tt = j * 8 + kt;     // linear tile counter
            if (tt < TN * 8 - 1) {
                // issue next tile's B staging; stays in flight across barrier
                const int ttn = tt + 1;
                const int jn = ttn >> 3, ktn = ttn & 7;
#pragma unroll
                for (int i = 0; i < 2; ++i)
                    load_lds16(bbase + (size_t)(jn * BN + i * 16) * D_DIM + ktn * BKB,
                               &Bl[ttn & 1][(w * 32 + i * 16) * BKB]);
                asm volatile("s_waitcnt vmcnt(2)" ::: "memory");  // cur done, next in flight
            } else {
                asm volatile("s_waitcnt vmcnt(0)" ::: "memory");  // final tile: drain
            }
            __builtin_amdgcn_sched_barrier(0);
            __builtin_amdgcn_s_barrier();    // cur B staging visible to all waves
            __builtin_amdgcn_sched_barrier(0);

            const int cur = tt & 1;
            longx2 af[4], bfr[4];
#pragma unroll
            for (int rt = 0; rt < 4; ++rt) {
                int r = wm * 64 + rt * 16 + lr;
                af[rt] = *reinterpret_cast<const longx2*>(
                    &Al[r * D_DIM + ((kt ^ (lr & 1)) << 6) + goff]);
            }
#pragma unroll
            for (int ct = 0; ct < 4; ++ct) {
                int r = wn * 64 + ct * 16 + lr;
                bfr[ct] = *reinterpret_cast<const longx2*>(&Bl[cur][r * BKB + goff]);
            }
            // quad q holds true k [kt*64+16q, +16): .x/.y feed the 2 k-step
            // MFMAs; identical permuted mapping for A and B -> exact dot.
            __builtin_amdgcn_s_setprio(1);
#pragma unroll
            for (int rt = 0; rt < 4; ++rt)
#pragma unroll
                for (int ct = 0; ct < 4; ++ct)
                    acc[rt][ct] = __builtin_amdgcn_mfma_f32_16x16x32_fp8_fp8(
                        af[rt].x, bfr[ct].x, acc[rt][ct], 0, 0, 0);
#pragma unroll
            for (int rt = 0; rt < 4; ++rt)
#pragma unroll
                for (int ct = 0; ct < 4; ++ct)
                    acc[rt][ct] = __builtin_amdgcn_mfma_f32_16x16x32_fp8_fp8(
                        af[rt].y, bfr[ct].y, acc[rt][ct], 0, 0, 0);
            __builtin_amdgcn_s_setprio(0);
            __builtin_amdgcn_sched_barrier(0);
            __builtin_amdgcn_s_barrier();    // buf[cur] reads done before overwrite
        }

        // ---- per-n-tile epilogue: REGISTER-ONLY (keeps vmcnt counts exact) ----
        // C/D layout: col = lane&15, row = (lane>>4)*4 + reg
        if (EPI == 0) {
#pragma unroll
            for (int rt = 0; rt < 4; ++rt)
#pragma unroll
                for (int reg = 0; reg < 4; ++reg) {
                    float v = 0.f;
#pragma unroll
                    for (int ct = 0; ct < 4; ++ct) v += __expf(acc[rt][ct][reg] * INV_T);
                    vac[rt][reg] += v;
                }
        } else {
#pragma unroll
            for (int rt = 0; rt < 4; ++rt)
#pragma unroll
                for (int reg = 0; reg < 4; ++reg) {
                    float s = Sv[rt][reg];
#pragma unroll
                    for (int ct = 0; ct < 4; ++ct) {
                        float pe = __expf(acc[rt][ct][reg] * INV_T);
                        lsum -= __logf(pe / (pe + s) + EPS_L);
                    }
                }
        }
    }

    // ---- final reductions + atomics (once per block) ----
    if (EPI == 0) {
#pragma unroll
        for (int rt = 0; rt < 4; ++rt)
#pragma unroll
            for (int reg = 0; reg < 4; ++reg) {
                float v = vac[rt][reg];
                v += __shfl_xor(v, 1);
                v += __shfl_xor(v, 2);
                v += __shfl_xor(v, 4);
                v += __shfl_xor(v, 8);
                if (lr == 0) {
                    int row = m0 + wm * 64 + rt * 16 + q * 4 + reg;
                    atomicAdd(&S[row], v);
                }
            }
    } else {
#pragma unroll
        for (int off = 1; off < 64; off <<= 1) lsum += __shfl_xor(lsum, off);
        if (lane == 0) atomicAdd(loss_sum, lsum);
    }
}

// ---- finalize: dot the (strided) column sums, emit the 4 scalars ----
__global__ void finalize_k(const float* __restrict__ csA, const float* __restrict__ csP,
                           const float* __restrict__ csN, const float* __restrict__ lsum,
                           float* __restrict__ out) {
    int tid = threadIdx.x;  // 512
    float av = csA[(size_t)tid * CS_STRIDE];
    float dp = av * csP[(size_t)tid * CS_STRIDE];
    float dn = av * csN[(size_t)tid * CS_STRIDE];
#pragma unroll
    for (int off = 1; off < 64; off <<= 1) {
        dp += __shfl_xor(dp, off);
        dn += __shfl_xor(dn, off);
    }
    __shared__ float red[16];
    int wid = tid >> 6, lane = tid & 63;
    if (lane == 0) { red[wid] = dp; red[8 + wid] = dn; }
    __syncthreads();
    if (tid == 0) {
        float sdp = 0.f, sdn = 0.f;
#pragma unroll
        for (int i = 0; i < 8; ++i) { sdp += red[i]; sdn += red[8 + i]; }
        float mean_pos = sdp * INV_T / ((float)B_ROWS * (float)P_ROWS);
        float mean_neg = sdn * INV_T / ((float)B_ROWS * (float)N_ROWS);
        out[0] = lsum[0] / ((float)B_ROWS * (float)P_ROWS);
        out[1] = mean_pos;
        out[2] = mean_neg;
        out[3] = mean_pos - mean_neg;
    }
}

extern "C" void kernel_launch(void* const* d_in, const int* in_sizes, int n_in,
                              void* d_out, int out_size, void* d_ws, size_t ws_size,
                              hipStream_t stream) {
    const float* anc = (const float*)d_in[0];
    const float* pos = (const float*)d_in[1];
    const float* neg = (const float*)d_in[2];
    float* out = (float*)d_out;

    fp8_t* a8 = (fp8_t*)d_ws;
    fp8_t* p8 = a8 + (size_t)B_ROWS * D_DIM;
    fp8_t* n8 = p8 + (size_t)P_ROWS * D_DIM;
    float* fsec = (float*)(n8 + (size_t)N_ROWS * D_DIM);  // 12MB offset, 64B-aligned
    float* S    = fsec;                        // 4096
    float* csA  = S + B_ROWS;                  // 512*16
    float* csP  = csA + D_DIM * CS_STRIDE;     // 512*16
    float* csN  = csP + D_DIM * CS_STRIDE;     // 512*16
    float* lsum = csN + D_DIM * CS_STRIDE;     // 1

    // ws is re-poisoned 0xAA before every launch -> zero all accumulators
    hipMemsetAsync(fsec, 0, (B_ROWS + 3 * D_DIM * CS_STRIDE + 1) * sizeof(float), stream);

    norm_colsum<<<1024, 256, 0, stream>>>(anc, pos, neg, a8, p8, n8, csA, csP, csN);

    // 512 blocks each (2/CU): neg sweeps 8 n-tiles/block, pos sweeps 2.
    gemm_epi<0, 8><<<dim3((N_ROWS / BN) / 8, B_ROWS / BM), 256, 0, stream>>>(a8, n8, S, nullptr);
    gemm_epi<1, 2><<<dim3((P_ROWS / BN) / 2, B_ROWS / BM), 256, 0, stream>>>(a8, p8, S, lsum);

    finalize_k<<<1, 512, 0, stream>>>(csA, csP, csN, lsum, out);
}

// Round 5
// 191.042 us; speedup vs baseline: 1.4998x; 1.1492x over previous
//
#include <hip/hip_runtime.h>
#include <hip/hip_bf16.h>

// InfoNCE: a[4096,512], p[4096,512], n[16384,512] f32 -> 4 f32 scalars.
// R9: A-in-registers + 4-deep B ring, ONE barrier/iter. R8 post-mortem: 62.5us
//     @ MfmaUtil 42.5%, and 2.1M bank-conflict cycles = +4cyc per A ds_read
//     (stride-512 parity layout not phase-clean). Fix: drop A from LDS
//     entirely -- per-lane A fragment over all K=512 is 8x16B = 32 VGPR
//     (8 waves x 16 rows, 512 thr). No A ds_reads, no A conflicts, 64KB LDS
//     freed. B: 4x8KB ring, prefetch distance 2, counted vmcnt(2) (1 load per
//     wave per tile); ring depth>=3 lets the top-of-iter barrier be the ONLY
//     barrier (writes to buf T+2; its readers done before barrier T-1).
//     Per iter: 1 stage + 8 B ds_read_b128 + 16 MFMA. launch_bounds(512,4)
//     -> VGPR cap 128 -> 16 waves/CU from 2 independent blocks (anti-phased).
//     A-gather loads true bytes kt*64+q*16 of each row == B's swizzled-slot
//     granule mapping -> per-(q,byte) true-k identical on both sides -> exact.
// ws layout: a8(2MB) p8(2MB) n8(8MB) | S[4096] csA[512*16] csP[512*16] csN[512*16] lsum[1]

#define D_DIM 512
#define B_ROWS 4096
#define P_ROWS 4096
#define N_ROWS 16384
#define INV_T 14.285714285714286f
#define EPS_L 1e-8f
#define CS_STRIDE 16  // colsum accumulators spread 64B apart -> atomics hit distinct lines

typedef unsigned char fp8_t;
typedef __attribute__((ext_vector_type(4))) float floatx4;   // MFMA C/D frag
typedef __attribute__((ext_vector_type(2))) long longx2;     // 16B = 2 MFMA operands
typedef unsigned int uint32;

// ---- fused: L2-normalize rows -> fp8 e4m3, and accumulate fp32 column sums ----
// grid = 1024 blocks x 256 thr. Segments: b<256 -> A, b<512 -> P, else -> N.
__global__ __launch_bounds__(256) void norm_colsum(
        const float* __restrict__ a, const float* __restrict__ p, const float* __restrict__ n,
        fp8_t* __restrict__ a8, fp8_t* __restrict__ p8, fp8_t* __restrict__ n8,
        float* __restrict__ csA, float* __restrict__ csP, float* __restrict__ csN) {
    const float* in; fp8_t* outp; float* cs; int rows, nb, bseg;
    int b = blockIdx.x;
    if (b < 256)      { in = a; outp = a8; cs = csA; rows = B_ROWS; nb = 256; bseg = b; }
    else if (b < 512) { in = p; outp = p8; cs = csP; rows = P_ROWS; nb = 256; bseg = b - 256; }
    else              { in = n; outp = n8; cs = csN; rows = N_ROWS; nb = 512; bseg = b - 512; }

    const int wave = threadIdx.x >> 6;
    const int lane = threadIdx.x & 63;

    float cs0[4] = {0.f, 0.f, 0.f, 0.f};
    float cs1[4] = {0.f, 0.f, 0.f, 0.f};

    for (int chunk = bseg; chunk < (rows >> 2); chunk += nb) {
        int r = chunk * 4 + wave;
        const float4* rp = reinterpret_cast<const float4*>(in + (size_t)r * D_DIM);
        float4 v0 = rp[lane];
        float4 v1 = rp[lane + 64];
        float ss = v0.x*v0.x + v0.y*v0.y + v0.z*v0.z + v0.w*v0.w
                 + v1.x*v1.x + v1.y*v1.y + v1.z*v1.z + v1.w*v1.w;
#pragma unroll
        for (int off = 1; off < 64; off <<= 1) ss += __shfl_xor(ss, off);
        float inv = 1.0f / fmaxf(sqrtf(ss), 1e-12f);
        float f0x = v0.x*inv, f0y = v0.y*inv, f0z = v0.z*inv, f0w = v0.w*inv;
        float f1x = v1.x*inv, f1y = v1.y*inv, f1z = v1.z*inv, f1w = v1.w*inv;
        cs0[0] += f0x; cs0[1] += f0y; cs0[2] += f0z; cs0[3] += f0w;
        cs1[0] += f1x; cs1[1] += f1y; cs1[2] += f1z; cs1[3] += f1w;
        // pack 4 floats -> 4 fp8 e4m3 bytes (RNE hw cvt)
        int pk0 = __builtin_amdgcn_cvt_pk_fp8_f32(f0x, f0y, 0, 0);
        pk0     = __builtin_amdgcn_cvt_pk_fp8_f32(f0z, f0w, pk0, 1);
        int pk1 = __builtin_amdgcn_cvt_pk_fp8_f32(f1x, f1y, 0, 0);
        pk1     = __builtin_amdgcn_cvt_pk_fp8_f32(f1z, f1w, pk1, 1);
        uint32* op = reinterpret_cast<uint32*>(outp + (size_t)r * D_DIM);
        op[lane]      = (uint32)pk0;   // bytes 4*lane .. 4*lane+3
        op[lane + 64] = (uint32)pk1;   // bytes 256+4*lane ..
    }

    // block-level colsum reduce: LDS atomics (4-way max contention), then one
    // global atomic per column per block, spread across 64B lines.
    __shared__ float csh[D_DIM];
    if (threadIdx.x < 256) { csh[threadIdx.x] = 0.f; csh[threadIdx.x + 256] = 0.f; }
    __syncthreads();
#pragma unroll
    for (int j = 0; j < 4; ++j) {
        atomicAdd(&csh[lane * 4 + j], cs0[j]);
        atomicAdd(&csh[256 + lane * 4 + j], cs1[j]);
    }
    __syncthreads();
    if (threadIdx.x < 256) {
        atomicAdd(&cs[(size_t)threadIdx.x * CS_STRIDE], csh[threadIdx.x]);
        atomicAdd(&cs[(size_t)(threadIdx.x + 256) * CS_STRIDE], csh[threadIdx.x + 256]);
    }
}

// ------------- fp8 MFMA GEMM: A in regs, B 4-ring LDS, 1 barrier/iter -------------
#define BM 128
#define BN 128
#define BKB 64   // K-elements per B tile == bytes per row per tile (fp8)
#define NBUF 4

typedef const __attribute__((address_space(1))) unsigned int* as1_u32p;
typedef __attribute__((address_space(3))) unsigned int* as3_u32p;

__device__ __forceinline__ void load_lds16(const void* g, void* l) {
    // each lane writes 16B at (wave-uniform l) + lane*16
    __builtin_amdgcn_global_load_lds((as1_u32p)g, (as3_u32p)l, 16, 0, 0);
}

// stage linear tile tt (n-tile tt>>3, k-chunk tt&7) into ring buf tt&3; this
// wave covers rows [w*16, w*16+16) of the BN=128 tile (64 lanes x 16B = 1KB).
#define STAGE_B(tt) load_lds16(                                                   \
        bbase + (size_t)((tt) >> 3) * (size_t)(BN * D_DIM) + (size_t)(((tt) & 7) * BKB), \
        &Bl[(tt) & 3][w * 16 * BKB])

// EPI==0: C = A@Bm^T, S[row] += sum_col exp(C*invT)           (neg pass)
// EPI==1: loss_sum += sum(-log(exp(C*invT)/(exp+S[row])+eps)) (pos pass)
// Block: 512 thr = 8 waves x 16 rows; sweeps TN n-tiles with A in registers.
template <int EPI, int TN>
__global__ __launch_bounds__(512, 4) void gemm_epi(const fp8_t* __restrict__ A,
                                                   const fp8_t* __restrict__ Bm,
                                                   float* __restrict__ S,
                                                   float* __restrict__ loss_sum) {
    __shared__ fp8_t Bl[NBUF][BN * BKB];   // 4 x 8 KB ring

    const int tid  = threadIdx.x;
    const int lane = tid & 63;
    const int w    = tid >> 6;          // wave 0..7 -> rows [w*16, w*16+16)
    const int m0   = blockIdx.y * BM;
    const int nt0  = blockIdx.x * TN;   // first n-tile index
    const int lr   = lane & 15;         // A/B input row within 16-tile (= out col)
    const int q    = lane >> 4;         // quad 0..3

    // ---- A panel -> registers: lane holds true bytes [kt*64+q*16, +16) of
    // row m0+w*16+lr for kt=0..7 (32 VGPR). Matches B's granule mapping.
    longx2 af[8];
    {
        const fp8_t* arow = A + (size_t)(m0 + w * 16 + lr) * D_DIM + q * 16;
#pragma unroll
        for (int kt = 0; kt < 8; ++kt)
            af[kt] = *reinterpret_cast<const longx2*>(arow + kt * 64);
    }

    // ---- B staging constants (R7's measured-zero-conflict scheme, stride 64):
    // LDS[r*64 + s*16] holds true granule s^((r>>1)&3) of row r.
    const int sr = lane >> 2;                        // row 0..15 within the 16-row slice
    const int sg = (lane & 3) ^ ((lane >> 3) & 3);   // inverse-swizzled source granule
    const fp8_t* bbase = Bm + (size_t)(nt0 * BN + w * 16 + sr) * D_DIM + sg * 16;
    // fragment read: lane wants true granule q of its row -> slot q^((r>>1)&3)
    const int goff = (q ^ ((lr >> 1) & 3)) << 4;

    float vac[4];   // EPI0: per-row exp-sum partials (rows q*4+reg), acc over n-tiles
    float Sv[4];    // EPI1: cached denominators
    float lsum = 0.f;
    if (EPI == 0) {
#pragma unroll
        for (int reg = 0; reg < 4; ++reg) vac[reg] = 0.f;
    } else {
#pragma unroll
        for (int reg = 0; reg < 4; ++reg)
            Sv[reg] = S[m0 + w * 16 + q * 4 + reg];
    }

    // prologue: tiles 0 and 1 in flight (1 load each per wave)
    STAGE_B(0);
    STAGE_B(1);

    for (int j = 0; j < TN; ++j) {
        floatx4 acc[8];
#pragma unroll
        for (int c = 0; c < 8; ++c) acc[c] = (floatx4){0.f, 0.f, 0.f, 0.f};

#pragma unroll
        for (int kt = 0; kt < 8; ++kt) {
            // prefetch tile T+2 into ring (kt+2)&3; its previous readers (tile
            // T-2) finished before barrier T-1, which we've already passed.
            if (kt < 6 || j < TN - 1) {
                const int tt = j * 8 + kt + 2;
                STAGE_B(tt);
                asm volatile("s_waitcnt vmcnt(2)" ::: "memory");  // tile T landed
            } else if (kt == 6) {
                asm volatile("s_waitcnt vmcnt(1)" ::: "memory");
            } else {
                asm volatile("s_waitcnt vmcnt(0)" ::: "memory");
            }
            __builtin_amdgcn_sched_barrier(0);
            __builtin_amdgcn_s_barrier();   // ONLY barrier: tile T resident for all
            __builtin_amdgcn_sched_barrier(0);

            const fp8_t* bl = &Bl[kt & 3][0];
            __builtin_amdgcn_s_setprio(1);
#pragma unroll
            for (int ct = 0; ct < 8; ++ct) {
                const int r = ct * 16 + lr;
                longx2 b = *reinterpret_cast<const longx2*>(&bl[r * BKB + goff]);
                // true k [kt*64+16q, +8) (.x) and +8 (.y) on BOTH sides -> exact
                acc[ct] = __builtin_amdgcn_mfma_f32_16x16x32_fp8_fp8(
                    af[kt].x, b.x, acc[ct], 0, 0, 0);
                acc[ct] = __builtin_amdgcn_mfma_f32_16x16x32_fp8_fp8(
                    af[kt].y, b.y, acc[ct], 0, 0, 0);
            }
            __builtin_amdgcn_s_setprio(0);
            __builtin_amdgcn_sched_barrier(0);
        }

        // ---- per-n-tile epilogue: register-only (vmcnt counts stay exact) ----
        // C/D layout: col = lane&15, row = (lane>>4)*4 + reg
        if (EPI == 0) {
#pragma unroll
            for (int reg = 0; reg < 4; ++reg) {
                float v = 0.f;
#pragma unroll
                for (int ct = 0; ct < 8; ++ct) v += __expf(acc[ct][reg] * INV_T);
                vac[reg] += v;
            }
        } else {
#pragma unroll
            for (int reg = 0; reg < 4; ++reg) {
                float s = Sv[reg];
#pragma unroll
                for (int ct = 0; ct < 8; ++ct) {
                    float pe = __expf(acc[ct][reg] * INV_T);
                    lsum -= __logf(pe / (pe + s) + EPS_L);
                }
            }
        }
    }

    // ---- final reductions + atomics (once per block) ----
    if (EPI == 0) {
#pragma unroll
        for (int reg = 0; reg < 4; ++reg) {
            float v = vac[reg];
            v += __shfl_xor(v, 1);
            v += __shfl_xor(v, 2);
            v += __shfl_xor(v, 4);
            v += __shfl_xor(v, 8);
            if (lr == 0) atomicAdd(&S[m0 + w * 16 + q * 4 + reg], v);
        }
    } else {
#pragma unroll
        for (int off = 1; off < 64; off <<= 1) lsum += __shfl_xor(lsum, off);
        // 8 waves -> 1 global atomic per block via LDS scratch (ring is dead)
        __syncthreads();
        float* red = reinterpret_cast<float*>(&Bl[0][0]);
        if (lane == 0) red[w] = lsum;
        __syncthreads();
        if (tid == 0) {
            float s = 0.f;
#pragma unroll
            for (int i = 0; i < 8; ++i) s += red[i];
            atomicAdd(loss_sum, s);
        }
    }
}

// ---- finalize: dot the (strided) column sums, emit the 4 scalars ----
__global__ void finalize_k(const float* __restrict__ csA, const float* __restrict__ csP,
                           const float* __restrict__ csN, const float* __restrict__ lsum,
                           float* __restrict__ out) {
    int tid = threadIdx.x;  // 512
    float av = csA[(size_t)tid * CS_STRIDE];
    float dp = av * csP[(size_t)tid * CS_STRIDE];
    float dn = av * csN[(size_t)tid * CS_STRIDE];
#pragma unroll
    for (int off = 1; off < 64; off <<= 1) {
        dp += __shfl_xor(dp, off);
        dn += __shfl_xor(dn, off);
    }
    __shared__ float red[16];
    int wid = tid >> 6, lane = tid & 63;
    if (lane == 0) { red[wid] = dp; red[8 + wid] = dn; }
    __syncthreads();
    if (tid == 0) {
        float sdp = 0.f, sdn = 0.f;
#pragma unroll
        for (int i = 0; i < 8; ++i) { sdp += red[i]; sdn += red[8 + i]; }
        float mean_pos = sdp * INV_T / ((float)B_ROWS * (float)P_ROWS);
        float mean_neg = sdn * INV_T / ((float)B_ROWS * (float)N_ROWS);
        out[0] = lsum[0] / ((float)B_ROWS * (float)P_ROWS);
        out[1] = mean_pos;
        out[2] = mean_neg;
        out[3] = mean_pos - mean_neg;
    }
}

extern "C" void kernel_launch(void* const* d_in, const int* in_sizes, int n_in,
                              void* d_out, int out_size, void* d_ws, size_t ws_size,
                              hipStream_t stream) {
    const float* anc = (const float*)d_in[0];
    const float* pos = (const float*)d_in[1];
    const float* neg = (const float*)d_in[2];
    float* out = (float*)d_out;

    fp8_t* a8 = (fp8_t*)d_ws;
    fp8_t* p8 = a8 + (size_t)B_ROWS * D_DIM;
    fp8_t* n8 = p8 + (size_t)P_ROWS * D_DIM;
    float* fsec = (float*)(n8 + (size_t)N_ROWS * D_DIM);  // 12MB offset, 64B-aligned
    float* S    = fsec;                        // 4096
    float* csA  = S + B_ROWS;                  // 512*16
    float* csP  = csA + D_DIM * CS_STRIDE;     // 512*16
    float* csN  = csP + D_DIM * CS_STRIDE;     // 512*16
    float* lsum = csN + D_DIM * CS_STRIDE;     // 1

    // ws is re-poisoned 0xAA before every launch -> zero all accumulators
    hipMemsetAsync(fsec, 0, (B_ROWS + 3 * D_DIM * CS_STRIDE + 1) * sizeof(float), stream);

    norm_colsum<<<1024, 256, 0, stream>>>(anc, pos, neg, a8, p8, n8, csA, csP, csN);

    // 512 blocks x 512 thr each (2 blocks/CU): neg sweeps 8 n-tiles, pos 2.
    gemm_epi<0, 8><<<dim3((N_ROWS / BN) / 8, B_ROWS / BM), 512, 0, stream>>>(a8, n8, S, nullptr);
    gemm_epi<1, 2><<<dim3((P_ROWS / BN) / 2, B_ROWS / BM), 512, 0, stream>>>(a8, p8, S, lsum);

    finalize_k<<<1, 512, 0, stream>>>(csA, csP, csN, lsum, out);
}